// Round 1
// baseline (543.053 us; speedup 1.0000x reference)
//
#include <hip/hip_runtime.h>

// ---------- types ----------
typedef short s16x8 __attribute__((ext_vector_type(8)));   // 8 bf16 (4 VGPRs), per guide
typedef float f32x4 __attribute__((ext_vector_type(4)));

static __device__ __forceinline__ unsigned short f2bf(float f) {
  unsigned u = __builtin_bit_cast(unsigned, f);
  unsigned r = (u + 0x7FFFu + ((u >> 16) & 1u)) >> 16;   // RNE; inputs finite
  return (unsigned short)r;
}

#define KD 512
// B = 16, T = 512, C = 19, E = 512, H = 8, HD = 64
// groups = B*T = 8192, rows = groups*19 = 155648

// ---------- kernel: convert weights fp32 -> bf16, rows 0..511 = w_q, 512..1023 = w_k ----------
__global__ void k_convw(const float* __restrict__ wq, const float* __restrict__ wk,
                        unsigned short* __restrict__ Wb) {
  int idx = blockIdx.x * 256 + threadIdx.x;   // 65536 threads, 8 elems each
  int f  = idx >> 6;
  int c8 = (idx & 63) << 3;
  const float* src = (f < 512) ? (wq + f * 512 + c8) : (wk + (f - 512) * 512 + c8);
  float4 v0 = *(const float4*)(src);
  float4 v1 = *(const float4*)(src + 4);
  s16x8 o;
  o[0] = (short)f2bf(v0.x); o[1] = (short)f2bf(v0.y); o[2] = (short)f2bf(v0.z); o[3] = (short)f2bf(v0.w);
  o[4] = (short)f2bf(v1.x); o[5] = (short)f2bf(v1.y); o[6] = (short)f2bf(v1.z); o[7] = (short)f2bf(v1.w);
  *(s16x8*)(Wb + f * 512 + c8) = o;
}

// ---------- kernel: QK = eeg @ [Wq^T | Wk^T] + bias, bf16 out ----------
// Persistent A-panel (128 rows x 512 K, bf16, padded stride 520) in LDS; A slices
// staged (fused into n==0's k-loop) so eeg is read from HBM exactly once.
// B tiles (128 x 32, padded stride 40) double-buffered, reg-staged (issue-early/write-late).
__global__ __launch_bounds__(256, 1)
void k_gemm(const float* __restrict__ A, const unsigned short* __restrict__ Wb,
            const float* __restrict__ bq, const float* __restrict__ bk,
            unsigned short* __restrict__ QK, long grow0) {
  __shared__ unsigned short Ap[128][520];       // 133,120 B
  __shared__ unsigned short Bs[2][128][40];     //  20,480 B  (total 153.6 KB)

  const int tid  = threadIdx.x;
  const int lane = tid & 63;
  const int wid  = tid >> 6;
  const int wr   = wid >> 1;      // wave row 0..1
  const int wc   = wid & 1;       // wave col 0..1
  const long arow0 = grow0 + (long)blockIdx.x * 128;

  const int sr = tid >> 1;            // staging row 0..127
  const int sc = (tid & 1) << 4;      // staging col 0 / 16

  // ---- prologue: stage A slice 0 + B(0,0) ----
  {
    const float* ap = A + (arow0 + sr) * KD + sc;
    float4 a0 = *(const float4*)(ap + 0);
    float4 a1 = *(const float4*)(ap + 4);
    float4 a2 = *(const float4*)(ap + 8);
    float4 a3 = *(const float4*)(ap + 12);
    s16x8 c0, c1;
    c0[0]=(short)f2bf(a0.x); c0[1]=(short)f2bf(a0.y); c0[2]=(short)f2bf(a0.z); c0[3]=(short)f2bf(a0.w);
    c0[4]=(short)f2bf(a1.x); c0[5]=(short)f2bf(a1.y); c0[6]=(short)f2bf(a1.z); c0[7]=(short)f2bf(a1.w);
    c1[0]=(short)f2bf(a2.x); c1[1]=(short)f2bf(a2.y); c1[2]=(short)f2bf(a2.z); c1[3]=(short)f2bf(a2.w);
    c1[4]=(short)f2bf(a3.x); c1[5]=(short)f2bf(a3.y); c1[6]=(short)f2bf(a3.z); c1[7]=(short)f2bf(a3.w);
    *(s16x8*)&Ap[sr][sc]     = c0;
    *(s16x8*)&Ap[sr][sc + 8] = c1;
    const unsigned short* bp = Wb + (long)sr * KD + sc;
    *(s16x8*)&Bs[0][sr][sc]     = *(const s16x8*)(bp);
    *(s16x8*)&Bs[0][sr][sc + 8] = *(const s16x8*)(bp + 8);
  }

  f32x4 acc[4][4] = {};
  int cur = 0;
  const int rlo = lane & 15;
  const int rhi = lane >> 4;

#pragma unroll 1
  for (int n = 0; n < 8; ++n) {
#pragma unroll 1
    for (int ks = 0; ks < 16; ++ks) {
      __syncthreads();   // staged buffers valid; other buffer free

      const bool haveNext = !(n == 7 && ks == 15);
      const int nn_ = (ks == 15) ? n + 1 : n;
      const int ks_ = (ks == 15) ? 0 : ks + 1;
      const bool stageA = (nn_ == 0);    // only during n==0

      float4 a0, a1, a2, a3; s16x8 b0, b1;
      if (haveNext) {
        if (stageA) {
          const float* ap = A + (arow0 + sr) * KD + ks_ * 32 + sc;
          a0 = *(const float4*)(ap + 0);
          a1 = *(const float4*)(ap + 4);
          a2 = *(const float4*)(ap + 8);
          a3 = *(const float4*)(ap + 12);
        }
        const unsigned short* bp = Wb + ((long)nn_ * 128 + sr) * KD + ks_ * 32 + sc;
        b0 = *(const s16x8*)(bp);
        b1 = *(const s16x8*)(bp + 8);
      }

      // ---- compute: 16 MFMAs from Ap slice ks and Bs[cur] ----
      s16x8 af[4], bf[4];
#pragma unroll
      for (int m = 0; m < 4; ++m)
        af[m] = *(const s16x8*)&Ap[wr * 64 + m * 16 + rlo][ks * 32 + rhi * 8];
#pragma unroll
      for (int nb = 0; nb < 4; ++nb)
        bf[nb] = *(const s16x8*)&Bs[cur][wc * 64 + nb * 16 + rlo][rhi * 8];
#pragma unroll
      for (int m = 0; m < 4; ++m)
#pragma unroll
        for (int nb = 0; nb < 4; ++nb)
          acc[m][nb] = __builtin_amdgcn_mfma_f32_16x16x32_bf16(af[m], bf[nb], acc[m][nb], 0, 0, 0);

      // ---- write staged data for next iter ----
      if (haveNext) {
        if (stageA) {
          s16x8 c0, c1;
          c0[0]=(short)f2bf(a0.x); c0[1]=(short)f2bf(a0.y); c0[2]=(short)f2bf(a0.z); c0[3]=(short)f2bf(a0.w);
          c0[4]=(short)f2bf(a1.x); c0[5]=(short)f2bf(a1.y); c0[6]=(short)f2bf(a1.z); c0[7]=(short)f2bf(a1.w);
          c1[0]=(short)f2bf(a2.x); c1[1]=(short)f2bf(a2.y); c1[2]=(short)f2bf(a2.z); c1[3]=(short)f2bf(a2.w);
          c1[4]=(short)f2bf(a3.x); c1[5]=(short)f2bf(a3.y); c1[6]=(short)f2bf(a3.z); c1[7]=(short)f2bf(a3.w);
          unsigned short* dst = &Ap[sr][ks_ * 32 + sc];
          *(s16x8*)dst       = c0;
          *(s16x8*)(dst + 8) = c1;
        }
        *(s16x8*)&Bs[cur ^ 1][sr][sc]     = b0;
        *(s16x8*)&Bs[cur ^ 1][sr][sc + 8] = b1;
      }
      cur ^= 1;
    }

    // ---- epilogue for this n-chunk: acc -> bf16 -> QK, then zero acc ----
#pragma unroll
    for (int nb = 0; nb < 4; ++nb) {
      int colg = n * 128 + wc * 64 + nb * 16 + rlo;
      float bias = (colg < 512) ? bq[colg] : bk[colg - 512];
#pragma unroll
      for (int m = 0; m < 4; ++m) {
        long rl = (long)blockIdx.x * 128 + wr * 64 + m * 16 + (rhi << 2);
#pragma unroll
        for (int j = 0; j < 4; ++j)
          QK[(rl + j) * 1024 + colg] = f2bf(acc[m][nb][j] + bias);
        acc[m][nb] = (f32x4){0.f, 0.f, 0.f, 0.f};
      }
    }
  }
}

// ---------- kernel: per-group attention -> atomic strength accumulation ----------
__global__ __launch_bounds__(256, 3)
void k_attn(const unsigned short* __restrict__ QK, float* __restrict__ acc, int g0) {
  __shared__ unsigned short Qs[19][1032];   // 39,216 B (padded stride: 2-way banks)
  __shared__ float Sc[8][19][20];           // 12,160 B
  __shared__ float red[256];

  const int tid  = threadIdx.x;
  const int lane = tid & 63;
  const int wid  = tid >> 6;
  const long gl  = blockIdx.x;

  // stage this group's Q|K rows (19 x 1024 bf16)
  const unsigned short* src = QK + gl * 19 * 1024;
  for (int c = tid; c < 2432; c += 256) {
    int row = c >> 7, c8 = (c & 127) << 3;
    *(s16x8*)&Qs[row][c8] = *(const s16x8*)(src + row * 1024 + c8);
  }
  __syncthreads();

  const int rlo = lane & 15, rhi = lane >> 4;
  const s16x8 z8 = {};
  // scores: wave wid handles heads 2*wid, 2*wid+1
#pragma unroll
  for (int hh = 0; hh < 2; ++hh) {
    const int h = wid * 2 + hh;
    f32x4 s[2][2] = {};
#pragma unroll
    for (int ks = 0; ks < 2; ++ks) {
      s16x8 qa[2], kb[2];
#pragma unroll
      for (int mi = 0; mi < 2; ++mi) {
        int r = mi * 16 + rlo;
        qa[mi] = (r < 19) ? *(const s16x8*)&Qs[r][h * 64 + ks * 32 + rhi * 8] : z8;
        kb[mi] = (r < 19) ? *(const s16x8*)&Qs[r][512 + h * 64 + ks * 32 + rhi * 8] : z8;
      }
#pragma unroll
      for (int mi = 0; mi < 2; ++mi)
#pragma unroll
        for (int nj = 0; nj < 2; ++nj)
          s[mi][nj] = __builtin_amdgcn_mfma_f32_16x16x32_bf16(qa[mi], kb[nj], s[mi][nj], 0, 0, 0);
    }
#pragma unroll
    for (int mi = 0; mi < 2; ++mi)
#pragma unroll
      for (int nj = 0; nj < 2; ++nj)
#pragma unroll
        for (int j = 0; j < 4; ++j) {
          int r = mi * 16 + rhi * 4 + j, c = nj * 16 + rlo;
          if (r < 19 && c < 19) Sc[h][r][c] = s[mi][nj][j] * 0.125f;  // 1/sqrt(64)
        }
  }
  __syncthreads();

  // row softmax: thread r<152 -> (h, i); partial = sum_{j>i} p_j
  float p = 0.f;
  if (tid < 152) {
    int h = tid / 19, i = tid - h * 19;
    float sv[19];
    float mx = -1e30f;
#pragma unroll
    for (int j = 0; j < 19; ++j) { sv[j] = Sc[h][i][j]; mx = fmaxf(mx, sv[j]); }
    float sum = 0.f, up = 0.f;
#pragma unroll
    for (int j = 0; j < 19; ++j) {
      float e = __expf(sv[j] - mx);
      sum += e;
      if (j > i) up += e;
    }
    p = up / sum;
  }
  red[tid] = p;
  __syncthreads();
  for (int off = 128; off > 0; off >>= 1) {
    if (tid < off) red[tid] += red[tid + off];
    __syncthreads();
  }
  if (tid == 0) {
    int b = (g0 + (int)blockIdx.x) >> 9;    // T = 512
    atomicAdd(&acc[b], red[0]);
  }
}

// ---------- kernel: finalize out[b] = clip(acc[b] / (8*171*512), 0, 1) ----------
__global__ void k_fin(const float* __restrict__ acc, float* __restrict__ out) {
  int t = threadIdx.x;
  if (t < 16) {
    float v = acc[t] * (1.0f / 700416.0f);
    out[t] = fminf(1.0f, fmaxf(0.0f, v));
  }
}

// ---------- host ----------
extern "C" void kernel_launch(void* const* d_in, const int* in_sizes, int n_in,
                              void* d_out, int out_size, void* d_ws, size_t ws_size,
                              hipStream_t stream) {
  const float* eeg = (const float*)d_in[0];
  const float* wq  = (const float*)d_in[1];
  const float* wk  = (const float*)d_in[2];
  const float* bq  = (const float*)d_in[3];
  const float* bk  = (const float*)d_in[4];
  float* out = (float*)d_out;

  char* ws = (char*)d_ws;
  unsigned short* Wb = (unsigned short*)ws;              // 1 MiB bf16 weights [1024][512]
  float* acc = (float*)(ws + (1 << 20));                 // 64 B accumulators
  unsigned short* QK = (unsigned short*)(ws + (1 << 20) + 256);

  // chunk groups in units of 128 (keeps rows divisible by 128: 128*19 = 2432 = 19 M-tiles)
  const long perChunkBytes = 128L * 19 * 1024 * 2;       // 4,980,736 B per 128 groups
  long avail = (long)ws_size - (1 << 20) - 256;
  long cap = avail / perChunkBytes;
  if (cap < 1) cap = 1;
  if (cap > 64) cap = 64;                                 // 64*128 = 8192 groups = everything
  const int chunk_groups = (int)cap * 128;

  hipMemsetAsync(acc, 0, 64, stream);
  k_convw<<<256, 256, 0, stream>>>(wq, wk, Wb);

  for (int g0 = 0; g0 < 8192; g0 += chunk_groups) {
    int cg = 8192 - g0; if (cg > chunk_groups) cg = chunk_groups;
    int nM = (cg * 19) / 128;                             // exact
    k_gemm<<<nM, 256, 0, stream>>>(eeg, Wb, bq, bk, QK, (long)g0 * 19);
    k_attn<<<cg, 256, 0, stream>>>(QK, acc, g0);
  }
  k_fin<<<1, 64, 0, stream>>>(acc, out);
}

// Round 2
// 507.253 us; speedup vs baseline: 1.0706x; 1.0706x over previous
//
#include <hip/hip_runtime.h>

// ---------- types ----------
typedef short s16x8 __attribute__((ext_vector_type(8)));   // 8 bf16 (4 VGPRs)
typedef float f32x4 __attribute__((ext_vector_type(4)));

static __device__ __forceinline__ unsigned short f2bf(float f) {
  unsigned u = __builtin_bit_cast(unsigned, f);
  unsigned r = (u + 0x7FFFu + ((u >> 16) & 1u)) >> 16;   // RNE; inputs finite
  return (unsigned short)r;
}

#define KD 512
// B = 16, T = 512, C = 19, E = 512, H = 8, HD = 64
// groups = B*T = 8192, rows = groups*19 = 155648

// ---------- kernel: convert weights fp32 -> bf16, rows 0..511 = w_q, 512..1023 = w_k ----------
__global__ void k_convw(const float* __restrict__ wq, const float* __restrict__ wk,
                        unsigned short* __restrict__ Wb) {
  int idx = blockIdx.x * 256 + threadIdx.x;   // 65536 threads, 8 elems each
  int f  = idx >> 6;
  int c8 = (idx & 63) << 3;
  const float* src = (f < 512) ? (wq + f * 512 + c8) : (wk + (f - 512) * 512 + c8);
  float4 v0 = *(const float4*)(src);
  float4 v1 = *(const float4*)(src + 4);
  s16x8 o;
  o[0] = (short)f2bf(v0.x); o[1] = (short)f2bf(v0.y); o[2] = (short)f2bf(v0.z); o[3] = (short)f2bf(v0.w);
  o[4] = (short)f2bf(v1.x); o[5] = (short)f2bf(v1.y); o[6] = (short)f2bf(v1.z); o[7] = (short)f2bf(v1.w);
  *(s16x8*)(Wb + f * 512 + c8) = o;
}

// ---------- kernel: QK = eeg @ [Wq^T | Wk^T] + bias, bf16 out ----------
// v2: 64-row persistent A panel in LDS (bf16, XOR-swizzled, staged once up front),
// B fragments read DIRECTLY from global (W is 1 MB, L2-resident) -> zero barriers
// in the main loop. 512 threads (8 waves); 64 KB LDS -> 2 blocks/CU = 4 waves/SIMD.
__global__ __launch_bounds__(512, 4)
void k_gemm(const float* __restrict__ A, const unsigned short* __restrict__ Wb,
            const float* __restrict__ bq, const float* __restrict__ bk,
            unsigned short* __restrict__ QK, long grow0) {
  __shared__ unsigned short Ap[64][512];       // 65,536 B, byte-addressed + swizzled

  const int tid  = threadIdx.x;
  const int lane = tid & 63;
  const int wid  = tid >> 6;                   // 0..7
  const int rlo  = lane & 15;
  const int rhi  = lane >> 4;
  const long arow0 = grow0 + (long)blockIdx.x * 64;
  char* lds = (char*)&Ap[0][0];

  // ---- stage A: 64 rows x 512 K, fp32 -> bf16, swizzled ----
  // 4096 chunks of 16B (8 bf16); 512 threads x 8 rounds; coalesced 32B fp32 reads.
#pragma unroll
  for (int r = 0; r < 8; ++r) {
    int id  = r * 512 + tid;
    int row = id >> 6;
    int kc  = id & 63;                         // 16B chunk index
    const float* ap = A + (arow0 + row) * KD + kc * 8;
    float4 v0 = *(const float4*)(ap);
    float4 v1 = *(const float4*)(ap + 4);
    s16x8 o;
    o[0]=(short)f2bf(v0.x); o[1]=(short)f2bf(v0.y); o[2]=(short)f2bf(v0.z); o[3]=(short)f2bf(v0.w);
    o[4]=(short)f2bf(v1.x); o[5]=(short)f2bf(v1.y); o[6]=(short)f2bf(v1.z); o[7]=(short)f2bf(v1.w);
    int byte = (kc * 16) ^ ((row & 7) << 4);   // XOR swizzle, 16B granularity
    *(s16x8*)(lds + row * 1024 + byte) = o;
  }
  __syncthreads();

  // ---- main: wave owns 64 rows x 128 cols (4 chunks of 32); no barriers ----
#pragma unroll 1
  for (int cc = 0; cc < 4; ++cc) {
    const int c0 = wid * 128 + cc * 32;
    f32x4 acc[4][2] = {};

#pragma unroll 4
    for (int ks = 0; ks < 16; ++ks) {
      s16x8 af[4], bf[2];
#pragma unroll
      for (int m = 0; m < 4; ++m) {
        int row  = m * 16 + rlo;
        int byte = (ks * 64 + rhi * 16) ^ ((row & 7) << 4);
        af[m] = *(const s16x8*)(lds + row * 1024 + byte);
      }
#pragma unroll
      for (int nb = 0; nb < 2; ++nb)
        bf[nb] = *(const s16x8*)(Wb + (long)(c0 + nb * 16 + rlo) * KD + ks * 32 + rhi * 8);
#pragma unroll
      for (int m = 0; m < 4; ++m)
#pragma unroll
        for (int nb = 0; nb < 2; ++nb)
          acc[m][nb] = __builtin_amdgcn_mfma_f32_16x16x32_bf16(af[m], bf[nb], acc[m][nb], 0, 0, 0);
    }

    // ---- epilogue for this col-chunk ----
#pragma unroll
    for (int nb = 0; nb < 2; ++nb) {
      int colg = c0 + nb * 16 + rlo;
      float bias = (colg < 512) ? bq[colg] : bk[colg - 512];
#pragma unroll
      for (int m = 0; m < 4; ++m) {
        long rl = (long)blockIdx.x * 64 + m * 16 + (rhi << 2);
#pragma unroll
        for (int j = 0; j < 4; ++j)
          QK[(rl + j) * 1024 + colg] = f2bf(acc[m][nb][j] + bias);
      }
    }
  }
}

// ---------- kernel: per-group attention -> atomic strength accumulation ----------
__global__ __launch_bounds__(256, 3)
void k_attn(const unsigned short* __restrict__ QK, float* __restrict__ acc, int g0) {
  __shared__ unsigned short Qs[19][1032];   // 39,216 B (padded stride: 2-way banks)
  __shared__ float Sc[8][19][20];           // 12,160 B
  __shared__ float red[256];

  const int tid  = threadIdx.x;
  const int lane = tid & 63;
  const int wid  = tid >> 6;
  const long gl  = blockIdx.x;

  // stage this group's Q|K rows (19 x 1024 bf16)
  const unsigned short* src = QK + gl * 19 * 1024;
  for (int c = tid; c < 2432; c += 256) {
    int row = c >> 7, c8 = (c & 127) << 3;
    *(s16x8*)&Qs[row][c8] = *(const s16x8*)(src + row * 1024 + c8);
  }
  __syncthreads();

  const int rlo = lane & 15, rhi = lane >> 4;
  const s16x8 z8 = {};
  // scores: wave wid handles heads 2*wid, 2*wid+1
#pragma unroll
  for (int hh = 0; hh < 2; ++hh) {
    const int h = wid * 2 + hh;
    f32x4 s[2][2] = {};
#pragma unroll
    for (int ks = 0; ks < 2; ++ks) {
      s16x8 qa[2], kb[2];
#pragma unroll
      for (int mi = 0; mi < 2; ++mi) {
        int r = mi * 16 + rlo;
        qa[mi] = (r < 19) ? *(const s16x8*)&Qs[r][h * 64 + ks * 32 + rhi * 8] : z8;
        kb[mi] = (r < 19) ? *(const s16x8*)&Qs[r][512 + h * 64 + ks * 32 + rhi * 8] : z8;
      }
#pragma unroll
      for (int mi = 0; mi < 2; ++mi)
#pragma unroll
        for (int nj = 0; nj < 2; ++nj)
          s[mi][nj] = __builtin_amdgcn_mfma_f32_16x16x32_bf16(qa[mi], kb[nj], s[mi][nj], 0, 0, 0);
    }
#pragma unroll
    for (int mi = 0; mi < 2; ++mi)
#pragma unroll
      for (int nj = 0; nj < 2; ++nj)
#pragma unroll
        for (int j = 0; j < 4; ++j) {
          int r = mi * 16 + rhi * 4 + j, c = nj * 16 + rlo;
          if (r < 19 && c < 19) Sc[h][r][c] = s[mi][nj][j] * 0.125f;  // 1/sqrt(64)
        }
  }
  __syncthreads();

  // row softmax: thread r<152 -> (h, i); partial = sum_{j>i} p_j
  float p = 0.f;
  if (tid < 152) {
    int h = tid / 19, i = tid - h * 19;
    float sv[19];
    float mx = -1e30f;
#pragma unroll
    for (int j = 0; j < 19; ++j) { sv[j] = Sc[h][i][j]; mx = fmaxf(mx, sv[j]); }
    float sum = 0.f, up = 0.f;
#pragma unroll
    for (int j = 0; j < 19; ++j) {
      float e = __expf(sv[j] - mx);
      sum += e;
      if (j > i) up += e;
    }
    p = up / sum;
  }
  red[tid] = p;
  __syncthreads();
  for (int off = 128; off > 0; off >>= 1) {
    if (tid < off) red[tid] += red[tid + off];
    __syncthreads();
  }
  if (tid == 0) {
    int b = (g0 + (int)blockIdx.x) >> 9;    // T = 512
    atomicAdd(&acc[b], red[0]);
  }
}

// ---------- kernel: finalize out[b] = clip(acc[b] / (8*171*512), 0, 1) ----------
__global__ void k_fin(const float* __restrict__ acc, float* __restrict__ out) {
  int t = threadIdx.x;
  if (t < 16) {
    float v = acc[t] * (1.0f / 700416.0f);
    out[t] = fminf(1.0f, fmaxf(0.0f, v));
  }
}

// ---------- host ----------
extern "C" void kernel_launch(void* const* d_in, const int* in_sizes, int n_in,
                              void* d_out, int out_size, void* d_ws, size_t ws_size,
                              hipStream_t stream) {
  const float* eeg = (const float*)d_in[0];
  const float* wq  = (const float*)d_in[1];
  const float* wk  = (const float*)d_in[2];
  const float* bq  = (const float*)d_in[3];
  const float* bk  = (const float*)d_in[4];
  float* out = (float*)d_out;

  char* ws = (char*)d_ws;
  unsigned short* Wb = (unsigned short*)ws;              // 1 MiB bf16 weights [1024][512]
  float* acc = (float*)(ws + (1 << 20));                 // 64 B accumulators
  unsigned short* QK = (unsigned short*)(ws + (1 << 20) + 256);

  // chunk groups in units of 128 (128 groups = 2432 rows = 38 blocks of 64 rows)
  const long perChunkBytes = 128L * 19 * 1024 * 2;       // 4,980,736 B per 128 groups
  long avail = (long)ws_size - (1 << 20) - 256;
  long cap = avail / perChunkBytes;
  if (cap < 1) cap = 1;
  if (cap > 64) cap = 64;                                 // 64*128 = 8192 groups = everything
  const int chunk_groups = (int)cap * 128;

  hipMemsetAsync(acc, 0, 64, stream);
  k_convw<<<256, 256, 0, stream>>>(wq, wk, Wb);

  for (int g0 = 0; g0 < 8192; g0 += chunk_groups) {
    int cg = 8192 - g0; if (cg > chunk_groups) cg = chunk_groups;
    int nM = (cg * 19) / 64;                              // exact (cg multiple of 128)
    k_gemm<<<nM, 512, 0, stream>>>(eeg, Wb, bq, bk, QK, (long)g0 * 19);
    k_attn<<<cg, 256, 0, stream>>>(QK, acc, g0);
  }
  k_fin<<<1, 64, 0, stream>>>(acc, out);
}